// Round 10
// baseline (198.958 us; speedup 1.0000x reference)
//
#include <hip/hip_runtime.h>
#include <hip/hip_bf16.h>
#include <stdint.h>
#include <stddef.h>

#define N_ 4096
#define D_ 64
#define I_ 512
#define O_ 512

#define BM 128
#define BN 128
#define SPLITS 4
#define DPG 16                 /* d-values per block */
#define PAIRS (DPG / 2)        /* 8 */
#define KXS 16                 /* K=512 / 32 per superstep */
#define NS (PAIRS * KXS)       /* 128 supersteps */
#define SLOT 8192              /* one tile: 128r x 32k bf16 packed [64][128B] */

typedef float  floatx4 __attribute__((ext_vector_type(4)));
typedef short  shortx8 __attribute__((ext_vector_type(8)));
typedef __bf16 bf16x8  __attribute__((ext_vector_type(8)));

__device__ __forceinline__ void gload_lds16(const void* g, void* l) {
  __builtin_amdgcn_global_load_lds(
      (const __attribute__((address_space(1))) void*)g,
      (__attribute__((address_space(3))) void*)l, 16, 0, 0);
}

__device__ __forceinline__ unsigned short f2bf(float f) {
  union { float f; unsigned int u; } c; c.f = f;
  unsigned int u = c.u;
  return (unsigned short)((u + 0x7fffu + ((u >> 16) & 1u)) >> 16);  // RNE
}

__device__ __forceinline__ void mfma_bf16(floatx4& c, shortx8 a, shortx8 b) {
  union { shortx8 s; bf16x8 h; } ua, ub;
  ua.s = a; ub.s = b;
  c = __builtin_amdgcn_mfma_f32_16x16x32_bf16(ua.h, ub.h, c, 0, 0, 0);
}

// ---------- pre-pass: x fp32 -> bf16 ----------
__global__ void k_cvt_x(const float* __restrict__ x, unsigned short* __restrict__ xb) {
  int idx = (blockIdx.x * blockDim.x + threadIdx.x) * 8;
  floatx4 a = *(const floatx4*)(x + idx);
  floatx4 b = *(const floatx4*)(x + idx + 4);
  shortx8 o;
  o[0] = (short)f2bf(a[0]); o[1] = (short)f2bf(a[1]);
  o[2] = (short)f2bf(a[2]); o[3] = (short)f2bf(a[3]);
  o[4] = (short)f2bf(b[0]); o[5] = (short)f2bf(b[1]);
  o[6] = (short)f2bf(b[2]); o[7] = (short)f2bf(b[3]);
  *(shortx8*)(xb + idx) = o;
}

// ---------- pre-pass: W[d][i][o] fp32 -> Wt[d][o][i] bf16 (transpose) ----------
__global__ void k_cvt_w(const float* __restrict__ w, unsigned short* __restrict__ wt) {
  __shared__ unsigned short T[64][72];
  int bid = blockIdx.x;
  int d  = bid >> 6;
  int it = (bid >> 3) & 7;
  int ot = bid & 7;
  int i0 = it * 64, o0 = ot * 64;
  int t = threadIdx.x;
  const float* wp = w + ((size_t)d * I_ + i0) * O_ + o0;
  #pragma unroll
  for (int j = 0; j < 16; ++j) {
    int idx = j * 256 + t;
    int r = idx >> 6, c = idx & 63;
    T[r][c] = f2bf(wp[(size_t)r * O_ + c]);
  }
  __syncthreads();
  unsigned short* op = wt + ((size_t)d * O_ + o0) * I_ + i0;
  #pragma unroll
  for (int j = 0; j < 16; ++j) {
    int idx = j * 256 + t;
    int r = idx >> 6, c = idx & 63;
    op[(size_t)r * I_ + c] = T[c][r];
  }
}

// ---------- bias: out[n,o] = sum_d var[n,d] * b1[d,o]  (zero-init + bias) ----------
__global__ void k_bias(const float* __restrict__ var, const float* __restrict__ b1,
                       float* __restrict__ out) {
  __shared__ float vs[16][64];
  int n0 = blockIdx.x * 16;
  int t = threadIdx.x;
  #pragma unroll
  for (int j = 0; j < 4; ++j) {
    int idx = j * 256 + t;
    vs[idx >> 6][idx & 63] = var[(size_t)n0 * D_ + idx];
  }
  __syncthreads();
  float a0[16], a1[16];
  #pragma unroll
  for (int r = 0; r < 16; ++r) { a0[r] = 0.f; a1[r] = 0.f; }
  for (int d = 0; d < D_; ++d) {
    float b0 = b1[(size_t)d * O_ + t];
    float bb = b1[(size_t)d * O_ + 256 + t];
    #pragma unroll
    for (int r = 0; r < 16; ++r) { a0[r] += vs[r][d] * b0; a1[r] += vs[r][d] * bb; }
  }
  #pragma unroll
  for (int r = 0; r < 16; ++r) {
    out[(size_t)(n0 + r) * O_ + t]       = a0[r];
    out[(size_t)(n0 + r) * O_ + 256 + t] = a1[r];
  }
}

// ---------- main: 128x128 d-paired, ring-2, __syncthreads drain, 2 blocks/CU ----------
// Sync = guide's T3-minimum recipe: stage(s+1) first, compute buf(s), one
// __syncthreads per superstep (compiler emits vmcnt(0)+lgkmcnt(0) drain before
// s_barrier — that IS the publication). The drain stall is hidden by the
// SECOND resident block per CU (56 KB LDS, launch_bounds(256,2)): block B's
// MFMA phase overlaps block A's read/drain phase — inter-block TLP instead of
// intra-block pipelining.
__global__ __launch_bounds__(256, 2) void k_gemm(
    const unsigned short* __restrict__ xb, const unsigned short* __restrict__ wt,
    const float* __restrict__ var, float* __restrict__ out) {
  __shared__ alignas(16) char lA[2][SLOT];        // 16 KB
  __shared__ alignas(16) char lB[2][2][SLOT];     // 32 KB
  __shared__ alignas(16) float lV[DPG * BM];      // 8 KB

  const int tid = threadIdx.x;
  const int bid = blockIdx.x;
  const int g  = bid & 15;          // (ot, split) — XCD-local W-slice sharing
  const int mt = bid >> 4;          // [0,32)
  const int ot = g >> 2, split = g & 3;
  const int brow = mt * BM, bcol = ot * BN, d0 = split * DPG;

  const int lane = tid & 63, wid = tid >> 6;
  const int wr = wid >> 1, wc = wid & 1;        // 2M x 2N waves, 64x64 each
  const int l15 = lane & 15, l4 = lane >> 4;

  // stage var transposed: lV[dd*BM + row] = var[brow+row][d0+dd]
  #pragma unroll
  for (int j = 0; j < (DPG * BM) / 256; ++j) {
    int idx = j * 256 + tid;
    int dd = idx >> 7, row = idx & (BM - 1);
    lV[idx] = var[(size_t)(brow + row) * D_ + d0 + dd];
  }

  const char* xbB = (const char*)xb;
  const char* wtB = (const char*)wt;
  const size_t IO2 = (size_t)I_ * O_ * 2;

  // ---- staging constants. Chunk c=1 is pb+4096 / gb+32768 (rl&7 invariant
  // under +32 rows, so the XOR term is identical).
  int pbA; size_t gbA;
  {
    int pb = tid << 4;                       // [0,4096)
    int rl = pb >> 7;                        // [0,32)
    int colG = (pb & 127) ^ ((rl & 7) << 4);
    int r_src = rl + ((colG >> 6) << 6);     // [0,128)
    int k_src = (colG & 63) >> 1;            // [0,32)
    pbA = pb;
    gbA = ((size_t)(brow + r_src) * I_ + k_src) * 2;
  }
  int pbB; size_t gbB;
  {
    int pb = tid << 4;
    int rl = pb >> 7;
    int colG = (pb & 127) ^ ((rl & 7) << 4);
    int r_src = rl + ((colG >> 6) << 6);
    int k_src = (colG & 63) >> 1;
    pbB = pb;
    gbB = ((size_t)(bcol + r_src) * I_ + k_src) * 2;
  }

  // ---- read offsets: r = w*64 + m*16 + l15 -> rl = m*16+l15, half = w ----
  int avOff[4], bvOff[4];
  #pragma unroll
  for (int m = 0; m < 4; ++m) {
    int rl = m * 16 + l15;                   // [0,64)
    avOff[m] = rl * 128 + (((wr << 6) + l4 * 16) ^ ((rl & 7) << 4));
    bvOff[m] = rl * 128 + (((wc << 6) + l4 * 16) ^ ((rl & 7) << 4));
  }

  auto stage = [&](int s, int buf) {
    const int kx = s & 15;
    const int d  = d0 + 2 * (s >> 4);
    char* la  = (char*)&lA[buf][0];
    char* lb0 = (char*)&lB[buf][0][0];
    char* lb1 = (char*)&lB[buf][1][0];
    const char* xsrc = xbB + gbA + (size_t)kx * 64;
    const char* wsrc = wtB + (size_t)d * IO2 + gbB + (size_t)kx * 64;
    #pragma unroll
    for (int c = 0; c < 2; ++c) {
      gload_lds16(xsrc + (size_t)c * 32768, la  + pbA + c * 4096);
      gload_lds16(wsrc + (size_t)c * 32768, lb0 + pbB + c * 4096);
      gload_lds16(wsrc + IO2 + (size_t)c * 32768, lb1 + pbB + c * 4096);
    }
  };

  const floatx4 vzero = {0.f, 0.f, 0.f, 0.f};
  floatx4 master[4][4], acc0[4][4], acc1[4][4];
  #pragma unroll
  for (int m = 0; m < 4; ++m)
    #pragma unroll
    for (int n = 0; n < 4; ++n) {
      master[m][n] = vzero; acc0[m][n] = vzero; acc1[m][n] = vzero;
    }

  stage(0, 0);
  __syncthreads();   // drains vmcnt+lgkm: stage(0) + lV published

  #pragma unroll 1
  for (int s = 0; s < NS; ++s) {
    const int buf = s & 1;
    if (s + 1 < NS) stage(s + 1, buf ^ 1);   // issue before compute (T3 recipe)

    const char* aS  = (const char*)&lA[buf][0];
    const char* bS0 = (const char*)&lB[buf][0][0];
    const char* bS1 = (const char*)&lB[buf][1][0];
    shortx8 av[4], bv[4];
    #pragma unroll
    for (int m = 0; m < 4; ++m) av[m] = *(const shortx8*)(aS + avOff[m]);
    #pragma unroll
    for (int n = 0; n < 4; ++n) bv[n] = *(const shortx8*)(bS0 + bvOff[n]);
    #pragma unroll
    for (int m = 0; m < 4; ++m)
      #pragma unroll
      for (int n = 0; n < 4; ++n) mfma_bf16(acc0[m][n], av[m], bv[n]);
    #pragma unroll
    for (int n = 0; n < 4; ++n) bv[n] = *(const shortx8*)(bS1 + bvOff[n]);
    #pragma unroll
    for (int m = 0; m < 4; ++m)
      #pragma unroll
      for (int n = 0; n < 4; ++n) mfma_bf16(acc1[m][n], av[m], bv[n]);

    if ((s & 15) == 15) {                    // pair end: fold into master
      int pp = s >> 4;
      #pragma unroll
      for (int m = 0; m < 4; ++m) {
        int rbase = wr * 64 + m * 16 + l4 * 4;
        floatx4 v0 = *(const floatx4*)&lV[(2 * pp) * BM + rbase];
        floatx4 v1 = *(const floatx4*)&lV[(2 * pp + 1) * BM + rbase];
        #pragma unroll
        for (int n = 0; n < 4; ++n) {
          #pragma unroll
          for (int r = 0; r < 4; ++r) {
            master[m][n][r] += v0[r] * acc0[m][n][r] + v1[r] * acc1[m][n][r];
            acc0[m][n][r] = 0.f;
            acc1[m][n][r] = 0.f;
          }
        }
      }
    }
    __syncthreads();   // publication of stage(s+1) + WAR fence for buf reuse
  }

  // epilogue: atomic add onto bias-initialized out
  #pragma unroll
  for (int m = 0; m < 4; ++m) {
    int row0 = brow + wr * 64 + m * 16 + l4 * 4;
    #pragma unroll
    for (int n = 0; n < 4; ++n) {
      int col = bcol + wc * 64 + n * 16 + l15;
      #pragma unroll
      for (int r = 0; r < 4; ++r)
        atomicAdd(out + (size_t)(row0 + r) * O_ + col, master[m][n][r]);
    }
  }
}

// ---------- fallback (only if ws too small for bf16 staging) ----------
__global__ void k_naive(const float* __restrict__ x, const float* __restrict__ var,
                        const float* __restrict__ w, const float* __restrict__ b1,
                        float* __restrict__ out) {
  int n = blockIdx.x;
  int o = blockIdx.y * 128 + threadIdx.x;
  const float* xp = x + (size_t)n * I_;
  float acc = 0.f;
  for (int d = 0; d < D_; ++d) {
    const float* wp = w + (size_t)d * I_ * O_ + o;
    float y = 0.f;
    for (int i = 0; i < I_; ++i) y += xp[i] * wp[(size_t)i * O_];
    acc += var[(size_t)n * D_ + d] * (y + b1[(size_t)d * O_ + o]);
  }
  out[(size_t)n * O_ + o] = acc;
}

extern "C" void kernel_launch(void* const* d_in, const int* in_sizes, int n_in,
                              void* d_out, int out_size, void* d_ws, size_t ws_size,
                              hipStream_t stream) {
  const float* x   = (const float*)d_in[0];
  const float* var = (const float*)d_in[1];
  const float* W   = (const float*)d_in[2];
  const float* b1  = (const float*)d_in[3];
  float* out = (float*)d_out;

  const size_t wt_bytes = (size_t)D_ * I_ * O_ * 2;  // 32 MB
  const size_t xb_bytes = (size_t)N_ * I_ * 2;       // 4 MB
  if (ws_size >= wt_bytes + xb_bytes) {
    unsigned short* wt = (unsigned short*)d_ws;
    unsigned short* xb = (unsigned short*)((char*)d_ws + wt_bytes);
    k_cvt_x<<<dim3((N_ * I_) / (256 * 8)), dim3(256), 0, stream>>>(x, xb);
    k_cvt_w<<<dim3(D_ * 64), dim3(256), 0, stream>>>(W, wt);
    k_bias<<<dim3(N_ / 16), dim3(256), 0, stream>>>(var, b1, out);
    k_gemm<<<dim3((N_ / BM) * (O_ / BN) * SPLITS), dim3(256), 0, stream>>>(xb, wt, var, out);
  } else {
    k_naive<<<dim3(N_, O_ / 128), dim3(128), 0, stream>>>(x, var, W, b1, out);
  }
}